// Round 1
// baseline (322.836 us; speedup 1.0000x reference)
//
#include <hip/hip_runtime.h>

#define TT 200
#define FF 32
#define HH 50

// readlane: broadcast lane k's register to all lanes (uniform/SGPR result).
__device__ __forceinline__ float rl(float v, int srclane) {
    return __int_as_float(__builtin_amdgcn_readlane(__float_as_int(v), srclane));
}

// tanh(x) = 1 - 2/(exp(2x)+1). v_exp_f32 + fast div: ~1e-6 rel error, handles
// large |x| (exp->inf -> tanh->1, exp->0 -> tanh->-1).
__device__ __forceinline__ float fast_tanh(float x) {
    float e = __expf(2.0f * x);
    return 1.0f - __fdividef(2.0f, e + 1.0f);
}

// One wave per batch row. Lane j (j<50) owns h[j] and the j-th columns of W,U
// in registers. h_k / x_f broadcasts via v_readlane (VALU pipe, zero LDS).
__global__ __launch_bounds__(256) void rnn_fused(
    const float* __restrict__ x, const float* __restrict__ W,
    const float* __restrict__ U, const float* __restrict__ b,
    const float* __restrict__ Wd, const float* __restrict__ bd,
    float* __restrict__ out, int B)
{
    const int lane = threadIdx.x & 63;
    const int row  = blockIdx.x * 4 + (threadIdx.x >> 6);
    if (row >= B) return;
    const int j = (lane < HH) ? lane : 0;   // clamp so idle lanes load safely

    // Weight columns in registers: W[:,j] (32) + U[:,j] (50) = 82 VGPRs.
    float w[FF];
#pragma unroll
    for (int f = 0; f < FF; ++f) w[f] = W[f * HH + j];
    float u[HH];
#pragma unroll
    for (int k = 0; k < HH; ++k) u[k] = U[k * HH + j];
    const float bj = b[j];

    const float* xr = x + (size_t)row * (TT * FF);
    float h  = 0.0f;
    float xv = (lane < FF) ? xr[lane] : 0.0f;   // lanes 0..31 hold x[row,t,:]

    for (int t = 0; t < TT; ++t) {
        // prefetch next timestep's x while computing this one
        float xn = 0.0f;
        if (lane < FF && t + 1 < TT) xn = xr[(t + 1) * FF + lane];

        float acc = bj;
#pragma unroll
        for (int f = 0; f < FF; ++f) acc += rl(xv, f) * w[f];
#pragma unroll
        for (int k = 0; k < HH; ++k) acc += rl(h, k) * u[k];

        h  = fast_tanh(acc);
        xv = xn;
    }

    // head: out[row] = relu(sum_j h[j]*Wd[j] + bd)
    float p = (lane < HH) ? h * Wd[j] : 0.0f;
#pragma unroll
    for (int m = 32; m >= 1; m >>= 1) p += __shfl_xor(p, m);
    if (lane == 0) out[row] = fmaxf(p + bd[0], 0.0f);
}

extern "C" void kernel_launch(void* const* d_in, const int* in_sizes, int n_in,
                              void* d_out, int out_size, void* d_ws, size_t ws_size,
                              hipStream_t stream) {
    const float* x  = (const float*)d_in[0];
    const float* W  = (const float*)d_in[1];
    const float* U  = (const float*)d_in[2];
    const float* b  = (const float*)d_in[3];
    const float* Wd = (const float*)d_in[4];
    const float* bd = (const float*)d_in[5];
    float* out = (float*)d_out;
    const int B = out_size;                 // 4096 rows, one output each
    dim3 grid((B + 3) / 4), block(256);     // 4 waves/block, 1 row/wave
    hipLaunchKernelGGL(rnn_fused, grid, block, 0, stream,
                       x, W, U, b, Wd, bd, out, B);
}

// Round 2
// 243.320 us; speedup vs baseline: 1.3268x; 1.3268x over previous
//
#include <hip/hip_runtime.h>

#define TT 200
#define FF 32
#define HH 50
#define HP 52   // hidden padded to multiple of 4 for float4 LDS reads

__device__ __forceinline__ float rl(float v, int srclane) {
    return __int_as_float(__builtin_amdgcn_readlane(__float_as_int(v), srclane));
}

// tanh(x) = 1 - 2/(exp(2x)+1); ~1e-6 rel, saturates correctly for large |x|.
__device__ __forceinline__ float fast_tanh(float x) {
    float e = __expf(2.0f * x);
    return 1.0f - __fdividef(2.0f, e + 1.0f);
}

// One wave per batch row. Lane j<50 owns h[j] and W[:,j], U[:,j] in VGPRs
// (launch_bounds(256,4) -> 128-VGPR cap so they actually stay resident).
// h broadcast via per-wave LDS region: 1 ds_write + 13 uniform ds_read_b128
// (LDS pipe, parallel to VALU). x broadcast via readlane. 4 accumulators
// break the FMA dependency chain.
__global__ __launch_bounds__(256, 4) void rnn_fused(
    const float* __restrict__ x, const float* __restrict__ W,
    const float* __restrict__ U, const float* __restrict__ b,
    const float* __restrict__ Wd, const float* __restrict__ bd,
    float* __restrict__ out, int B)
{
    __shared__ float sh[4][HP];
    const int lane = threadIdx.x & 63;
    const int wid  = threadIdx.x >> 6;
    const int row  = blockIdx.x * 4 + wid;
    if (row >= B) return;
    const int j = (lane < HH) ? lane : 0;   // clamp for safe loads

    float w[FF];
#pragma unroll
    for (int f = 0; f < FF; ++f) w[f] = W[f * HH + j];
    float u[HP];
#pragma unroll
    for (int k = 0; k < HH; ++k) u[k] = U[k * HH + j];
    u[HH] = 0.0f; u[HH + 1] = 0.0f;         // pad columns multiply to zero
    const float bj = b[j];

    float* shw = sh[wid];                   // per-wave region: no syncthreads needed
    if (lane < HP) shw[lane] = 0.0f;        // h0 = 0 (incl. pad slots)

    const float* xr = x + (size_t)row * (TT * FF);
    float h  = 0.0f;
    float xv = (lane < FF) ? xr[lane] : 0.0f;

    for (int t = 0; t < TT; ++t) {
        // prefetch next timestep's x (clamped re-read on last step: harmless)
        const int tn = (t + 1 < TT) ? (t + 1) : (TT - 1);
        const float xn = (lane < FF) ? xr[tn * FF + lane] : 0.0f;

        float a0 = bj, a1 = 0.0f, a2 = 0.0f, a3 = 0.0f;

        // x part: readlane broadcast (VALU) — issued first to give the
        // ds_write->ds_read dependency time to drain.
#pragma unroll
        for (int f = 0; f < FF; f += 4) {
            a0 = fmaf(rl(xv, f + 0), w[f + 0], a0);
            a1 = fmaf(rl(xv, f + 1), w[f + 1], a1);
            a2 = fmaf(rl(xv, f + 2), w[f + 2], a2);
            a3 = fmaf(rl(xv, f + 3), w[f + 3], a3);
        }
        // h part: uniform-address float4 LDS broadcast (conflict-free)
#pragma unroll
        for (int q = 0; q < HP / 4; ++q) {
            const float4 hb = ((const float4*)shw)[q];
            a0 = fmaf(hb.x, u[4 * q + 0], a0);
            a1 = fmaf(hb.y, u[4 * q + 1], a1);
            a2 = fmaf(hb.z, u[4 * q + 2], a2);
            a3 = fmaf(hb.w, u[4 * q + 3], a3);
        }

        h = fast_tanh((a0 + a1) + (a2 + a3));
        if (lane < HH) shw[lane] = h;       // publish h_t for next step
        xv = xn;
    }

    // head: out[row] = relu(sum_j h[j]*Wd[j] + bd)
    float p = (lane < HH) ? h * Wd[j] : 0.0f;
#pragma unroll
    for (int m = 32; m >= 1; m >>= 1) p += __shfl_xor(p, m);
    if (lane == 0) out[row] = fmaxf(p + bd[0], 0.0f);
}

extern "C" void kernel_launch(void* const* d_in, const int* in_sizes, int n_in,
                              void* d_out, int out_size, void* d_ws, size_t ws_size,
                              hipStream_t stream) {
    const float* x  = (const float*)d_in[0];
    const float* W  = (const float*)d_in[1];
    const float* U  = (const float*)d_in[2];
    const float* b  = (const float*)d_in[3];
    const float* Wd = (const float*)d_in[4];
    const float* bd = (const float*)d_in[5];
    float* out = (float*)d_out;
    const int B = out_size;                 // 4096 rows
    dim3 grid((B + 3) / 4), block(256);     // 1 row per wave, 4 waves per block
    hipLaunchKernelGGL(rnn_fused, grid, block, 0, stream,
                       x, W, U, b, Wd, bd, out, B);
}